// Round 4
// baseline (124.865 us; speedup 1.0000x reference)
//
#include <hip/hip_runtime.h>
#include <stdint.h>
#include <stddef.h>

typedef _Float16 half_t;
typedef __attribute__((ext_vector_type(8))) _Float16 h16x8;
typedef __attribute__((ext_vector_type(4))) _Float16 h16x4;
typedef __attribute__((ext_vector_type(4))) float f32x4;

#define MFMA16(a, b, c) __builtin_amdgcn_mfma_f32_16x16x32_f16(a, b, c, 0, 0, 0)

// XOR swizzle: 16B-slot permutation within a 128B row. slot in [0,8), returns
// half-index offset within the row.
#define SW(row, slot) ((((slot) ^ ((row) & 7))) * 8)

// ---------------------------------------------------------------------------
// Kernel 0a: convert x fp32 -> fp16
// ---------------------------------------------------------------------------
__global__ __launch_bounds__(256) void cvt_x_kernel(const float* __restrict__ x,
                                                    half_t* __restrict__ xh, int n8) {
    int i = blockIdx.x * blockDim.x + threadIdx.x;
    if (i >= n8) return;
    const float4* xv = (const float4*)x;
    float4 a = xv[i * 2 + 0];
    float4 b = xv[i * 2 + 1];
    h16x8 o;
    o[0] = (half_t)a.x; o[1] = (half_t)a.y; o[2] = (half_t)a.z; o[3] = (half_t)a.w;
    o[4] = (half_t)b.x; o[5] = (half_t)b.y; o[6] = (half_t)b.z; o[7] = (half_t)b.w;
    ((h16x8*)xh)[i] = o;
}

// ---------------------------------------------------------------------------
// Kernel 0b: transpose + convert W [k][n] fp32 -> Wt [p][n][k] fp16
// ---------------------------------------------------------------------------
__global__ __launch_bounds__(256) void cvt_w_kernel(const float* __restrict__ Wq,
                                                    const float* __restrict__ Wk,
                                                    const float* __restrict__ Wv,
                                                    half_t* __restrict__ Wt) {
    __shared__ float t[32][33];
    const float* W = (blockIdx.z == 0) ? Wq : ((blockIdx.z == 1) ? Wk : Wv);
    int k0 = blockIdx.y * 32, n0 = blockIdx.x * 32;
    int tid = threadIdx.x;
    int r = tid >> 3;          // 0..31
    int c4 = (tid & 7) * 4;    // 0..28
    float4 v = *(const float4*)&W[(size_t)(k0 + r) * 1024 + n0 + c4];
    t[r][c4 + 0] = v.x; t[r][c4 + 1] = v.y; t[r][c4 + 2] = v.z; t[r][c4 + 3] = v.w;
    __syncthreads();
    half_t* o = Wt + (size_t)blockIdx.z * 1024 * 1024 + (size_t)(n0 + r) * 1024 + k0 + c4;
    h16x4 h;
    h[0] = (half_t)t[c4 + 0][r];
    h[1] = (half_t)t[c4 + 1][r];
    h[2] = (half_t)t[c4 + 2][r];
    h[3] = (half_t)t[c4 + 3][r];
    *(h16x4*)o = h;
}

// ---------------------------------------------------------------------------
// Kernel 1: QKV projection GEMM.  Y = xh @ W + b.
// Q,K stored [bh][s][hd] fp16;  V stored TRANSPOSED [bh][hd][s] fp16.
// grid (8, 32, 3), block 256 (4 waves 2x2), tile 128x128, BK=32.
// ---------------------------------------------------------------------------
__global__ __launch_bounds__(256) void gemm_qkv_kernel(
    const half_t* __restrict__ xh,   // [4096][1024]
    const half_t* __restrict__ Wt,   // [3][1024 n][1024 k]
    const float* __restrict__ bq, const float* __restrict__ bk,
    const float* __restrict__ bv,
    half_t* __restrict__ qkv)
{
    const int p = blockIdx.z;
    const float* bias = (p == 0) ? bq : ((p == 1) ? bk : bv);
    const half_t* Wp = Wt + (size_t)p * 1024 * 1024;
    const int n0 = blockIdx.x * 128, m0 = blockIdx.y * 128;

    __shared__ half_t Al[128][40];
    __shared__ half_t Bl[128][40];

    const int tid = threadIdx.x;
    const int lane = tid & 63, wid = tid >> 6;
    const int wm = wid >> 1, wn = wid & 1;
    const int g = lane >> 4, r = lane & 15;

    const int sr = tid >> 2;
    const int sc = (tid & 3) * 8;

    f32x4 acc[4][4];
#pragma unroll
    for (int a = 0; a < 4; a++)
#pragma unroll
        for (int c = 0; c < 4; c++) acc[a][c] = (f32x4){0.f, 0.f, 0.f, 0.f};

    for (int k0 = 0; k0 < 1024; k0 += 32) {
        __syncthreads();
        *(h16x8*)&Al[sr][sc]      = *(const h16x8*)&xh[(size_t)(m0 + sr) * 1024 + k0 + sc];
        *(h16x8*)&Al[sr + 64][sc] = *(const h16x8*)&xh[(size_t)(m0 + sr + 64) * 1024 + k0 + sc];
        *(h16x8*)&Bl[sr][sc]      = *(const h16x8*)&Wp[(size_t)(n0 + sr) * 1024 + k0 + sc];
        *(h16x8*)&Bl[sr + 64][sc] = *(const h16x8*)&Wp[(size_t)(n0 + sr + 64) * 1024 + k0 + sc];
        __syncthreads();

        h16x8 af[4], bf[4];
#pragma unroll
        for (int mi = 0; mi < 4; mi++)
            af[mi] = *(const h16x8*)&Al[wm * 64 + mi * 16 + r][g * 8];
#pragma unroll
        for (int ni = 0; ni < 4; ni++)
            bf[ni] = *(const h16x8*)&Bl[wn * 64 + ni * 16 + r][g * 8];
#pragma unroll
        for (int mi = 0; mi < 4; mi++)
#pragma unroll
            for (int ni = 0; ni < 4; ni++)
                acc[mi][ni] = MFMA16(af[mi], bf[ni], acc[mi][ni]);
    }

    float bn[4];
#pragma unroll
    for (int ni = 0; ni < 4; ni++) bn[ni] = bias[n0 + wn * 64 + ni * 16 + r];

    if (p == 2) {
        // V: store transposed [bh][hd][s], packed 4 consecutive s per store
        half_t* outp = qkv + (size_t)2 * 4194304;
#pragma unroll
        for (int mi = 0; mi < 4; mi++) {
            int m = m0 + wm * 64 + mi * 16 + g * 4;
            int b = m >> 11, s = m & 2047;
#pragma unroll
            for (int ni = 0; ni < 4; ni++) {
                int n = n0 + wn * 64 + ni * 16 + r;
                int h = n >> 6, hd = n & 63;
                h16x4 pk;
#pragma unroll
                for (int i = 0; i < 4; i++) pk[i] = (half_t)(acc[mi][ni][i] + bn[ni]);
                *(h16x4*)&outp[((size_t)(b * 16 + h) * 64 + hd) * 2048 + s] = pk;
            }
        }
    } else {
        half_t* outp = qkv + (size_t)p * 4194304;
#pragma unroll
        for (int mi = 0; mi < 4; mi++) {
#pragma unroll
            for (int ni = 0; ni < 4; ni++) {
                int n = n0 + wn * 64 + ni * 16 + r;
                int h = n >> 6, hd = n & 63;
#pragma unroll
                for (int i = 0; i < 4; i++) {
                    int m = m0 + wm * 64 + mi * 16 + g * 4 + i;
                    int b = m >> 11, s = m & 2047;
                    float v = acc[mi][ni][i] + bn[ni];
                    outp[(((size_t)(b * 16 + h) * 2048 + s) << 6) + hd] = (half_t)v;
                }
            }
        }
    }
}

// ---------------------------------------------------------------------------
// Kernel 2: flash attention.  grid (S/128=16, B*H=32), block 512 (8 waves).
// Swapped QK^T (in-lane softmax in exp2 domain), XOR-swizzled LDS (T2),
// double-buffered K/V with async-stage split (T14), defer-max (T13).
// ---------------------------------------------------------------------------
__global__ __launch_bounds__(512, 4) void attn_kernel(
    const half_t* __restrict__ Qg,  // [32][2048][64]
    const half_t* __restrict__ Kg,  // [32][2048][64]
    const half_t* __restrict__ Vtg, // [32][64][2048]  (V transposed)
    float* __restrict__ out)        // [B][S][1024]
{
    __shared__ half_t Kl[2][64][64];    // 128B rows, XOR-swizzled 16B slots
    __shared__ half_t Vl[2][64][64];
    __shared__ half_t Pl[8][16][64];

    const int tid = threadIdx.x;
    const int lane = tid & 63, wid = tid >> 6;
    const int g = lane >> 4, r = lane & 15;
    const int bh = blockIdx.y;
    const int b = bh >> 4, h = bh & 15;
    const half_t* Qb = Qg + (size_t)bh * 131072;
    const half_t* Kb = Kg + (size_t)bh * 131072;
    const half_t* Vb = Vtg + (size_t)bh * 131072;
    const int q0 = blockIdx.x * 128 + wid * 16;

    // hoisted Q fragments, pre-scaled by log2(e) for exp2-domain softmax
    h16x8 qf[2];
    qf[0] = *(const h16x8*)&Qb[(size_t)(q0 + r) * 64 + g * 8];
    qf[1] = *(const h16x8*)&Qb[(size_t)(q0 + r) * 64 + 32 + g * 8];
    qf[0] *= (half_t)1.44269504f;
    qf[1] *= (half_t)1.44269504f;

    f32x4 o[4];
#pragma unroll
    for (int d = 0; d < 4; d++) o[d] = (f32x4){0.f, 0.f, 0.f, 0.f};
    float m_run = -1e30f, l_run = 0.f;   // per-lane state for q = lane&15 (exp2 domain)

    const int srow = tid >> 3;          // 0..63
    const int sslot = tid & 7;          // 16B slot 0..7
    const int sc8 = sslot * 8;

    // prologue: stage tile 0 (swizzled writes)
    {
        h16x8 k0 = *(const h16x8*)&Kb[srow * 64 + sc8];
        h16x8 v0 = *(const h16x8*)&Vb[(size_t)srow * 2048 + sc8];
        *(h16x8*)&Kl[0][srow][SW(srow, sslot)] = k0;
        *(h16x8*)&Vl[0][srow][SW(srow, sslot)] = v0;
    }

    h16x8 kreg, vreg;
    int cur = 0;

    auto compute_tile = [&](int cb) {
        // QK^T (swapped): lane holds E[k = kc*16 + g*4 + i][q = lane&15]
        f32x4 e[4];
#pragma unroll
        for (int kc = 0; kc < 4; kc++) {
            e[kc] = (f32x4){0.f, 0.f, 0.f, 0.f};
#pragma unroll
            for (int t = 0; t < 2; t++) {
                h16x8 kf = *(const h16x8*)&Kl[cb][kc * 16 + r][SW(r, t * 4 + g)];
                e[kc] = MFMA16(kf, qf[t], e[kc]);
            }
        }

        // in-lane tile max (max3-friendly nests) + cross-g reduce
        float t0 = fmaxf(fmaxf(e[0][0], e[0][1]), e[0][2]);
        float t1 = fmaxf(fmaxf(e[0][3], e[1][0]), e[1][1]);
        float t2 = fmaxf(fmaxf(e[1][2], e[1][3]), e[2][0]);
        float t3 = fmaxf(fmaxf(e[2][1], e[2][2]), e[2][3]);
        float t4 = fmaxf(fmaxf(e[3][0], e[3][1]), e[3][2]);
        float tm = fmaxf(fmaxf(t0, t1), fmaxf(fmaxf(t2, t3), fmaxf(t4, e[3][3])));
        tm = fmaxf(tm, __shfl_xor(tm, 16));
        tm = fmaxf(tm, __shfl_xor(tm, 32));

        // defer-max: only rescale when some row's max grew by > 8 (exp2 domain)
        if (!__all(tm <= m_run + 8.f)) {
            float nm = fmaxf(m_run, tm);
            float sc = exp2f(m_run - nm);
            m_run = nm;
            l_run *= sc;
#pragma unroll
            for (int i = 0; i < 4; i++) {
                float sci = __shfl(sc, (lane & 48) | (g * 4 + i));
#pragma unroll
                for (int d = 0; d < 4; d++) o[d][i] *= sci;
            }
        }

        float ps = 0.f;
#pragma unroll
        for (int kc = 0; kc < 4; kc++)
#pragma unroll
            for (int i = 0; i < 4; i++) {
                float pv = exp2f(e[kc][i] - m_run);
                e[kc][i] = pv;
                ps += pv;
            }
        ps += __shfl_xor(ps, 16);
        ps += __shfl_xor(ps, 32);
        l_run += ps;

        // P -> per-wave LDS (swizzled b64 writes), then PV
#pragma unroll
        for (int kc = 0; kc < 4; kc++) {
            h16x4 pk;
#pragma unroll
            for (int i = 0; i < 4; i++) pk[i] = (half_t)e[kc][i];
            *(h16x4*)&Pl[wid][r][SW(r, 2 * kc + (g >> 1)) + (g & 1) * 4] = pk;
        }
        asm volatile("s_waitcnt lgkmcnt(0)" ::: "memory");
        __builtin_amdgcn_sched_barrier(0);

#pragma unroll
        for (int ks = 0; ks < 2; ks++) {
            h16x8 pf = *(const h16x8*)&Pl[wid][r][SW(r, ks * 4 + g)];
#pragma unroll
            for (int d = 0; d < 4; d++) {
                h16x8 vf = *(const h16x8*)&Vl[cb][d * 16 + r][SW(r, ks * 4 + g)];
                o[d] = MFMA16(pf, vf, o[d]);
            }
        }
    };

    for (int kt = 0; kt < 31; ++kt) {
        // issue next-tile global loads (latency hides under compute)
        kreg = *(const h16x8*)&Kb[(kt + 1) * 4096 + srow * 64 + sc8];
        vreg = *(const h16x8*)&Vb[(size_t)srow * 2048 + (kt + 1) * 64 + sc8];
        __syncthreads();
        compute_tile(cur);
        // write next tile into the other buffer (vmcnt wait lands here)
        *(h16x8*)&Kl[cur ^ 1][srow][SW(srow, sslot)] = kreg;
        *(h16x8*)&Vl[cur ^ 1][srow][SW(srow, sslot)] = vreg;
        cur ^= 1;
    }
    __syncthreads();
    compute_tile(cur);

    // epilogue
#pragma unroll
    for (int i = 0; i < 4; i++) {
        float li = __shfl(l_run, (lane & 48) | (g * 4 + i));
        float inv = 1.0f / li;
        int s = q0 + g * 4 + i;
        float* op = out + (size_t)(b * 2048 + s) * 1024 + h * 64 + r;
#pragma unroll
        for (int d = 0; d < 4; d++) op[d * 16] = o[d][i] * inv;
    }
}

// ---------------------------------------------------------------------------
extern "C" void kernel_launch(void* const* d_in, const int* in_sizes, int n_in,
                              void* d_out, int out_size, void* d_ws, size_t ws_size,
                              hipStream_t stream) {
    const float* x  = (const float*)d_in[0];
    const float* Wq = (const float*)d_in[1];
    const float* bq = (const float*)d_in[2];
    const float* Wk = (const float*)d_in[3];
    const float* bk = (const float*)d_in[4];
    const float* Wv = (const float*)d_in[5];
    const float* bv = (const float*)d_in[6];
    float* out = (float*)d_out;

    half_t* xh  = (half_t*)d_ws;
    half_t* Wt  = (half_t*)((char*)d_ws + (size_t)8 * 1024 * 1024);
    half_t* qkv = (half_t*)((char*)d_ws + (size_t)14 * 1024 * 1024);
    half_t* Qh  = qkv;
    half_t* Kh  = qkv + (size_t)4194304;
    half_t* Vth = qkv + (size_t)8388608;

    cvt_x_kernel<<<2048, 256, 0, stream>>>(x, xh, 524288);
    cvt_w_kernel<<<dim3(32, 32, 3), 256, 0, stream>>>(Wq, Wk, Wv, Wt);
    gemm_qkv_kernel<<<dim3(8, 32, 3), 256, 0, stream>>>(xh, Wt, bq, bk, bv, qkv);
    attn_kernel<<<dim3(16, 32), 512, 0, stream>>>(Qh, Kh, Vth, out);
}

// Round 6
// 115.160 us; speedup vs baseline: 1.0843x; 1.0843x over previous
//
#include <hip/hip_runtime.h>
#include <stdint.h>
#include <stddef.h>

typedef _Float16 half_t;
typedef __attribute__((ext_vector_type(8))) _Float16 h16x8;
typedef __attribute__((ext_vector_type(4))) _Float16 h16x4;
typedef __attribute__((ext_vector_type(4))) float f32x4;

#define MFMA16(a, b, c) __builtin_amdgcn_mfma_f32_16x16x32_f16(a, b, c, 0, 0, 0)
#define EXP2(x) __builtin_amdgcn_exp2f(x)

// XOR swizzle: 16B-slot permutation within a 128B row. slot in [0,8).
#define SW(row, slot) ((((slot) ^ ((row) & 7))) * 8)

// ---------------------------------------------------------------------------
// Kernel 0a: convert x fp32 -> fp16
// ---------------------------------------------------------------------------
__global__ __launch_bounds__(256) void cvt_x_kernel(const float* __restrict__ x,
                                                    half_t* __restrict__ xh, int n8) {
    int i = blockIdx.x * blockDim.x + threadIdx.x;
    if (i >= n8) return;
    const float4* xv = (const float4*)x;
    float4 a = xv[i * 2 + 0];
    float4 b = xv[i * 2 + 1];
    h16x8 o;
    o[0] = (half_t)a.x; o[1] = (half_t)a.y; o[2] = (half_t)a.z; o[3] = (half_t)a.w;
    o[4] = (half_t)b.x; o[5] = (half_t)b.y; o[6] = (half_t)b.z; o[7] = (half_t)b.w;
    ((h16x8*)xh)[i] = o;
}

// ---------------------------------------------------------------------------
// Kernel 0b: transpose + convert W [k][n] fp32 -> Wt [p][n][k] fp16
// ---------------------------------------------------------------------------
__global__ __launch_bounds__(256) void cvt_w_kernel(const float* __restrict__ Wq,
                                                    const float* __restrict__ Wk,
                                                    const float* __restrict__ Wv,
                                                    half_t* __restrict__ Wt) {
    __shared__ float t[32][33];
    const float* W = (blockIdx.z == 0) ? Wq : ((blockIdx.z == 1) ? Wk : Wv);
    int k0 = blockIdx.y * 32, n0 = blockIdx.x * 32;
    int tid = threadIdx.x;
    int r = tid >> 3;          // 0..31
    int c4 = (tid & 7) * 4;    // 0..28
    float4 v = *(const float4*)&W[(size_t)(k0 + r) * 1024 + n0 + c4];
    t[r][c4 + 0] = v.x; t[r][c4 + 1] = v.y; t[r][c4 + 2] = v.z; t[r][c4 + 3] = v.w;
    __syncthreads();
    half_t* o = Wt + (size_t)blockIdx.z * 1024 * 1024 + (size_t)(n0 + r) * 1024 + k0 + c4;
    h16x4 h;
    h[0] = (half_t)t[c4 + 0][r];
    h[1] = (half_t)t[c4 + 1][r];
    h[2] = (half_t)t[c4 + 2][r];
    h[3] = (half_t)t[c4 + 3][r];
    *(h16x4*)o = h;
}

// ---------------------------------------------------------------------------
// Kernel 1: QKV projection GEMM with register-prefetched staging.
// Q,K stored [bh][s][hd] fp16;  V stored TRANSPOSED [bh][hd][s] fp16.
// grid (8, 32, 3), block 256 (4 waves 2x2), tile 128x128, BK=32.
// ---------------------------------------------------------------------------
__global__ __launch_bounds__(256) void gemm_qkv_kernel(
    const half_t* __restrict__ xh,   // [4096][1024]
    const half_t* __restrict__ Wt,   // [3][1024 n][1024 k]
    const float* __restrict__ bq, const float* __restrict__ bk,
    const float* __restrict__ bv,
    half_t* __restrict__ qkv)
{
    const int p = blockIdx.z;
    const float* bias = (p == 0) ? bq : ((p == 1) ? bk : bv);
    const half_t* Wp = Wt + (size_t)p * 1024 * 1024;
    const int n0 = blockIdx.x * 128, m0 = blockIdx.y * 128;

    __shared__ half_t Al[128][40];
    __shared__ half_t Bl[128][40];

    const int tid = threadIdx.x;
    const int lane = tid & 63, wid = tid >> 6;
    const int wm = wid >> 1, wn = wid & 1;
    const int g = lane >> 4, r = lane & 15;

    const int sr = tid >> 2;
    const int sc = (tid & 3) * 8;

    f32x4 acc[4][4];
#pragma unroll
    for (int a = 0; a < 4; a++)
#pragma unroll
        for (int c = 0; c < 4; c++) acc[a][c] = (f32x4){0.f, 0.f, 0.f, 0.f};

    h16x8 ra0, ra1, rb0, rb1;
    // prologue: load K-step 0 into regs
    ra0 = *(const h16x8*)&xh[(size_t)(m0 + sr) * 1024 + sc];
    ra1 = *(const h16x8*)&xh[(size_t)(m0 + sr + 64) * 1024 + sc];
    rb0 = *(const h16x8*)&Wp[(size_t)(n0 + sr) * 1024 + sc];
    rb1 = *(const h16x8*)&Wp[(size_t)(n0 + sr + 64) * 1024 + sc];

    for (int k0 = 0; k0 < 1024; k0 += 32) {
        __syncthreads();
        *(h16x8*)&Al[sr][sc]      = ra0;
        *(h16x8*)&Al[sr + 64][sc] = ra1;
        *(h16x8*)&Bl[sr][sc]      = rb0;
        *(h16x8*)&Bl[sr + 64][sc] = rb1;
        __syncthreads();

        // issue next K-step's loads AFTER the barrier (latency hides under MFMA)
        int kn = (k0 + 32) & 1023;   // wraps to 0 on last iter (harmless reload)
        ra0 = *(const h16x8*)&xh[(size_t)(m0 + sr) * 1024 + kn + sc];
        ra1 = *(const h16x8*)&xh[(size_t)(m0 + sr + 64) * 1024 + kn + sc];
        rb0 = *(const h16x8*)&Wp[(size_t)(n0 + sr) * 1024 + kn + sc];
        rb1 = *(const h16x8*)&Wp[(size_t)(n0 + sr + 64) * 1024 + kn + sc];

        h16x8 af[4], bf[4];
#pragma unroll
        for (int mi = 0; mi < 4; mi++)
            af[mi] = *(const h16x8*)&Al[wm * 64 + mi * 16 + r][g * 8];
#pragma unroll
        for (int ni = 0; ni < 4; ni++)
            bf[ni] = *(const h16x8*)&Bl[wn * 64 + ni * 16 + r][g * 8];
#pragma unroll
        for (int mi = 0; mi < 4; mi++)
#pragma unroll
            for (int ni = 0; ni < 4; ni++)
                acc[mi][ni] = MFMA16(af[mi], bf[ni], acc[mi][ni]);
    }

    float bn[4];
#pragma unroll
    for (int ni = 0; ni < 4; ni++) bn[ni] = bias[n0 + wn * 64 + ni * 16 + r];

    if (p == 2) {
        // V: store transposed [bh][hd][s], packed 4 consecutive s per store
        half_t* outp = qkv + (size_t)2 * 4194304;
#pragma unroll
        for (int mi = 0; mi < 4; mi++) {
            int m = m0 + wm * 64 + mi * 16 + g * 4;
            int b = m >> 11, s = m & 2047;
#pragma unroll
            for (int ni = 0; ni < 4; ni++) {
                int n = n0 + wn * 64 + ni * 16 + r;
                int h = n >> 6, hd = n & 63;
                h16x4 pk;
#pragma unroll
                for (int i = 0; i < 4; i++) pk[i] = (half_t)(acc[mi][ni][i] + bn[ni]);
                *(h16x4*)&outp[((size_t)(b * 16 + h) * 64 + hd) * 2048 + s] = pk;
            }
        }
    } else {
        half_t* outp = qkv + (size_t)p * 4194304;
#pragma unroll
        for (int mi = 0; mi < 4; mi++) {
#pragma unroll
            for (int ni = 0; ni < 4; ni++) {
                int n = n0 + wn * 64 + ni * 16 + r;
                int h = n >> 6, hd = n & 63;
#pragma unroll
                for (int i = 0; i < 4; i++) {
                    int m = m0 + wm * 64 + mi * 16 + g * 4 + i;
                    int b = m >> 11, s = m & 2047;
                    float v = acc[mi][ni][i] + bn[ni];
                    outp[(((size_t)(b * 16 + h) * 2048 + s) << 6) + hd] = (half_t)v;
                }
            }
        }
    }
}

// ---------------------------------------------------------------------------
// Kernel 2: flash attention.  grid (S/128=16, B*H=32), block 512 (8 waves).
// Swapped QK^T, exp2-domain softmax (native v_exp), XOR-swizzled LDS,
// double-buffered K/V with loads issued AFTER the barrier (no vmcnt drain
// at s_barrier), branch-hoisted defer-max.
// ---------------------------------------------------------------------------
__global__ __launch_bounds__(512, 4) void attn_kernel(
    const half_t* __restrict__ Qg,  // [32][2048][64]
    const half_t* __restrict__ Kg,  // [32][2048][64]
    const half_t* __restrict__ Vtg, // [32][64][2048]  (V transposed)
    float* __restrict__ out)        // [B][S][1024]
{
    __shared__ half_t Kl[2][64][64];    // 128B rows, XOR-swizzled 16B slots
    __shared__ half_t Vl[2][64][64];
    __shared__ half_t Pl[8][16][64];

    const int tid = threadIdx.x;
    const int lane = tid & 63, wid = tid >> 6;
    const int g = lane >> 4, r = lane & 15;
    const int bh = blockIdx.y;
    const int b = bh >> 4, h = bh & 15;
    const half_t* Qb = Qg + (size_t)bh * 131072;
    const half_t* Kb = Kg + (size_t)bh * 131072;
    const half_t* Vb = Vtg + (size_t)bh * 131072;
    const int q0 = blockIdx.x * 128 + wid * 16;

    // hoisted Q fragments, pre-scaled by log2(e) for exp2-domain softmax
    h16x8 qf[2];
    qf[0] = *(const h16x8*)&Qb[(size_t)(q0 + r) * 64 + g * 8];
    qf[1] = *(const h16x8*)&Qb[(size_t)(q0 + r) * 64 + 32 + g * 8];
    qf[0] *= (half_t)1.44269504f;
    qf[1] *= (half_t)1.44269504f;

    f32x4 o[4];
#pragma unroll
    for (int d = 0; d < 4; d++) o[d] = (f32x4){0.f, 0.f, 0.f, 0.f};
    float m_run = 0.f, l_run = 0.f;   // exp2-domain; m=0 init is safe

    const int srow = tid >> 3;          // 0..63
    const int sslot = tid & 7;          // 16B slot 0..7
    const int sc8 = sslot * 8;

    // prologue: stage tile 0 (swizzled writes)
    {
        h16x8 k0 = *(const h16x8*)&Kb[srow * 64 + sc8];
        h16x8 v0 = *(const h16x8*)&Vb[(size_t)srow * 2048 + sc8];
        *(h16x8*)&Kl[0][srow][SW(srow, sslot)] = k0;
        *(h16x8*)&Vl[0][srow][SW(srow, sslot)] = v0;
    }

    h16x8 kreg, vreg;
    int cur = 0;

    auto compute_tile = [&](int cb) {
        // QK^T (swapped): lane holds E[k = kc*16 + g*4 + i][q = lane&15]
        f32x4 e[4];
#pragma unroll
        for (int kc = 0; kc < 4; kc++) {
            e[kc] = (f32x4){0.f, 0.f, 0.f, 0.f};
#pragma unroll
            for (int t = 0; t < 2; t++) {
                h16x8 kf = *(const h16x8*)&Kl[cb][kc * 16 + r][SW(r, t * 4 + g)];
                e[kc] = MFMA16(kf, qf[t], e[kc]);
            }
        }

        // tile max (feeds only the rare-rescale branch, off critical path)
        float t0 = fmaxf(fmaxf(e[0][0], e[0][1]), e[0][2]);
        float t1 = fmaxf(fmaxf(e[0][3], e[1][0]), e[1][1]);
        float t2 = fmaxf(fmaxf(e[1][2], e[1][3]), e[2][0]);
        float t3 = fmaxf(fmaxf(e[2][1], e[2][2]), e[2][3]);
        float t4 = fmaxf(fmaxf(e[3][0], e[3][1]), e[3][2]);
        float tm = fmaxf(fmaxf(t0, t1), fmaxf(fmaxf(t2, t3), fmaxf(t4, e[3][3])));
        tm = fmaxf(tm, __shfl_xor(tm, 16));
        tm = fmaxf(tm, __shfl_xor(tm, 32));

        // unconditional exp with the CURRENT m_run (starts immediately after MFMA)
        float ps0 = 0.f, ps1 = 0.f, ps2 = 0.f, ps3 = 0.f;
#pragma unroll
        for (int i = 0; i < 4; i++) { e[0][i] = EXP2(e[0][i] - m_run); ps0 += e[0][i]; }
#pragma unroll
        for (int i = 0; i < 4; i++) { e[1][i] = EXP2(e[1][i] - m_run); ps1 += e[1][i]; }
#pragma unroll
        for (int i = 0; i < 4; i++) { e[2][i] = EXP2(e[2][i] - m_run); ps2 += e[2][i]; }
#pragma unroll
        for (int i = 0; i < 4; i++) { e[3][i] = EXP2(e[3][i] - m_run); ps3 += e[3][i]; }

        // rare fix-up: a row's max grew by more than 8 (exp2 domain)
        if (!__all(tm <= m_run + 8.f)) {
            float nm = fmaxf(m_run, tm);
            float sc = EXP2(m_run - nm);
            m_run = nm;
            l_run *= sc;
#pragma unroll
            for (int kc = 0; kc < 4; kc++)
#pragma unroll
                for (int i = 0; i < 4; i++) e[kc][i] *= sc;
            ps0 *= sc; ps1 *= sc; ps2 *= sc; ps3 *= sc;
#pragma unroll
            for (int i = 0; i < 4; i++) {
                float sci = __shfl(sc, (lane & 48) | (g * 4 + i));
#pragma unroll
                for (int d = 0; d < 4; d++) o[d][i] *= sci;
            }
        }

        float ps = (ps0 + ps1) + (ps2 + ps3);
        ps += __shfl_xor(ps, 16);
        ps += __shfl_xor(ps, 32);
        l_run += ps;

        // P -> per-wave LDS (swizzled b64 writes), then PV
#pragma unroll
        for (int kc = 0; kc < 4; kc++) {
            h16x4 pk;
#pragma unroll
            for (int i = 0; i < 4; i++) pk[i] = (half_t)e[kc][i];
            *(h16x4*)&Pl[wid][r][SW(r, 2 * kc + (g >> 1)) + (g & 1) * 4] = pk;
        }
        asm volatile("s_waitcnt lgkmcnt(0)" ::: "memory");
        __builtin_amdgcn_sched_barrier(0);

#pragma unroll
        for (int ks = 0; ks < 2; ks++) {
            h16x8 pf = *(const h16x8*)&Pl[wid][r][SW(r, ks * 4 + g)];
#pragma unroll
            for (int d = 0; d < 4; d++) {
                h16x8 vf = *(const h16x8*)&Vl[cb][d * 16 + r][SW(r, ks * 4 + g)];
                o[d] = MFMA16(pf, vf, o[d]);
            }
        }
    };

    for (int kt = 0; kt < 32; ++kt) {
        int ktn = (kt + 1) & 31;   // wraps on last iter (harmless reload of tile 0)
        __syncthreads();
        // issue next-tile loads AFTER the barrier: no vmcnt drain at s_barrier,
        // latency hides under compute_tile
        kreg = *(const h16x8*)&Kb[ktn * 4096 + srow * 64 + sc8];
        vreg = *(const h16x8*)&Vb[(size_t)srow * 2048 + ktn * 64 + sc8];
        compute_tile(cur);
        *(h16x8*)&Kl[cur ^ 1][srow][SW(srow, sslot)] = kreg;
        *(h16x8*)&Vl[cur ^ 1][srow][SW(srow, sslot)] = vreg;
        cur ^= 1;
    }

    // epilogue
#pragma unroll
    for (int i = 0; i < 4; i++) {
        float li = __shfl(l_run, (lane & 48) | (g * 4 + i));
        float inv = 1.0f / li;
        int s = q0 + g * 4 + i;
        float* op = out + (size_t)(b * 2048 + s) * 1024 + h * 64 + r;
#pragma unroll
        for (int d = 0; d < 4; d++) op[d * 16] = o[d][i] * inv;
    }
}

// ---------------------------------------------------------------------------
extern "C" void kernel_launch(void* const* d_in, const int* in_sizes, int n_in,
                              void* d_out, int out_size, void* d_ws, size_t ws_size,
                              hipStream_t stream) {
    const float* x  = (const float*)d_in[0];
    const float* Wq = (const float*)d_in[1];
    const float* bq = (const float*)d_in[2];
    const float* Wk = (const float*)d_in[3];
    const float* bk = (const float*)d_in[4];
    const float* Wv = (const float*)d_in[5];
    const float* bv = (const float*)d_in[6];
    float* out = (float*)d_out;

    half_t* xh  = (half_t*)d_ws;
    half_t* Wt  = (half_t*)((char*)d_ws + (size_t)8 * 1024 * 1024);
    half_t* qkv = (half_t*)((char*)d_ws + (size_t)14 * 1024 * 1024);
    half_t* Qh  = qkv;
    half_t* Kh  = qkv + (size_t)4194304;
    half_t* Vth = qkv + (size_t)8388608;

    cvt_x_kernel<<<2048, 256, 0, stream>>>(x, xh, 524288);
    cvt_w_kernel<<<dim3(32, 32, 3), 256, 0, stream>>>(Wq, Wk, Wv, Wt);
    gemm_qkv_kernel<<<dim3(8, 32, 3), 256, 0, stream>>>(xh, Wt, bq, bk, bv, qkv);
    attn_kernel<<<dim3(16, 32), 512, 0, stream>>>(Qh, Kh, Vth, out);
}

// Round 7
// 109.284 us; speedup vs baseline: 1.1426x; 1.0538x over previous
//
#include <hip/hip_runtime.h>
#include <stdint.h>
#include <stddef.h>

typedef _Float16 half_t;
typedef __attribute__((ext_vector_type(8))) _Float16 h16x8;
typedef __attribute__((ext_vector_type(4))) _Float16 h16x4;
typedef __attribute__((ext_vector_type(4))) float f32x4;

#define MFMA16(a, b, c) __builtin_amdgcn_mfma_f32_16x16x32_f16(a, b, c, 0, 0, 0)
#define EXP2(x) __builtin_amdgcn_exp2f(x)

// XOR swizzle: 16B-slot permutation within a 128B row. slot in [0,8).
#define SW(row, slot) ((((slot) ^ ((row) & 7))) * 8)

// ---------------------------------------------------------------------------
// Kernel 0a: convert x fp32 -> fp16
// ---------------------------------------------------------------------------
__global__ __launch_bounds__(256) void cvt_x_kernel(const float* __restrict__ x,
                                                    half_t* __restrict__ xh, int n8) {
    int i = blockIdx.x * blockDim.x + threadIdx.x;
    if (i >= n8) return;
    const float4* xv = (const float4*)x;
    float4 a = xv[i * 2 + 0];
    float4 b = xv[i * 2 + 1];
    h16x8 o;
    o[0] = (half_t)a.x; o[1] = (half_t)a.y; o[2] = (half_t)a.z; o[3] = (half_t)a.w;
    o[4] = (half_t)b.x; o[5] = (half_t)b.y; o[6] = (half_t)b.z; o[7] = (half_t)b.w;
    ((h16x8*)xh)[i] = o;
}

// ---------------------------------------------------------------------------
// Kernel 0b: transpose + convert W [k][n] fp32 -> Wt [p][n][k] fp16
// ---------------------------------------------------------------------------
__global__ __launch_bounds__(256) void cvt_w_kernel(const float* __restrict__ Wq,
                                                    const float* __restrict__ Wk,
                                                    const float* __restrict__ Wv,
                                                    half_t* __restrict__ Wt) {
    __shared__ float t[32][33];
    const float* W = (blockIdx.z == 0) ? Wq : ((blockIdx.z == 1) ? Wk : Wv);
    int k0 = blockIdx.y * 32, n0 = blockIdx.x * 32;
    int tid = threadIdx.x;
    int r = tid >> 3;          // 0..31
    int c4 = (tid & 7) * 4;    // 0..28
    float4 v = *(const float4*)&W[(size_t)(k0 + r) * 1024 + n0 + c4];
    t[r][c4 + 0] = v.x; t[r][c4 + 1] = v.y; t[r][c4 + 2] = v.z; t[r][c4 + 3] = v.w;
    __syncthreads();
    half_t* o = Wt + (size_t)blockIdx.z * 1024 * 1024 + (size_t)(n0 + r) * 1024 + k0 + c4;
    h16x4 h;
    h[0] = (half_t)t[c4 + 0][r];
    h[1] = (half_t)t[c4 + 1][r];
    h[2] = (half_t)t[c4 + 2][r];
    h[3] = (half_t)t[c4 + 3][r];
    *(h16x4*)o = h;
}

// ---------------------------------------------------------------------------
// Kernel 1: QKV projection GEMM, BK=64, 4-deep reg prefetch.
// Q,K stored [bh][s][hd] fp16;  V stored TRANSPOSED [bh][hd][s] fp16.
// grid (8, 32, 3), block 256 (4 waves 2x2), tile 128x128.
// ---------------------------------------------------------------------------
__global__ __launch_bounds__(256, 2) void gemm_qkv_kernel(
    const half_t* __restrict__ xh,   // [4096][1024]
    const half_t* __restrict__ Wt,   // [3][1024 n][1024 k]
    const float* __restrict__ bq, const float* __restrict__ bk,
    const float* __restrict__ bv,
    half_t* __restrict__ qkv)
{
    const int p = blockIdx.z;
    const float* bias = (p == 0) ? bq : ((p == 1) ? bk : bv);
    const half_t* Wp = Wt + (size_t)p * 1024 * 1024;
    const int n0 = blockIdx.x * 128, m0 = blockIdx.y * 128;

    __shared__ half_t Al[128][72];   // 144B rows: fragment phases conflict-free
    __shared__ half_t Bl[128][72];

    const int tid = threadIdx.x;
    const int lane = tid & 63, wid = tid >> 6;
    const int wm = wid >> 1, wn = wid & 1;
    const int g = lane >> 4, r = lane & 15;

    const int srow = tid >> 3;       // 0..31
    const int scol = (tid & 7) * 8;  // 0..56

    f32x4 acc[4][4];
#pragma unroll
    for (int a = 0; a < 4; a++)
#pragma unroll
        for (int c = 0; c < 4; c++) acc[a][c] = (f32x4){0.f, 0.f, 0.f, 0.f};

    h16x8 ra[4], rb[4];
#pragma unroll
    for (int i = 0; i < 4; i++) {
        ra[i] = *(const h16x8*)&xh[(size_t)(m0 + srow + i * 32) * 1024 + scol];
        rb[i] = *(const h16x8*)&Wp[(size_t)(n0 + srow + i * 32) * 1024 + scol];
    }

    for (int k0 = 0; k0 < 1024; k0 += 64) {
        __syncthreads();
#pragma unroll
        for (int i = 0; i < 4; i++) {
            *(h16x8*)&Al[srow + i * 32][scol] = ra[i];
            *(h16x8*)&Bl[srow + i * 32][scol] = rb[i];
        }
        __syncthreads();

        // next K-step's loads issued AFTER the barrier (hide under MFMA)
        int kn = (k0 + 64) & 1023;   // wraps on last iter (harmless reload)
#pragma unroll
        for (int i = 0; i < 4; i++) {
            ra[i] = *(const h16x8*)&xh[(size_t)(m0 + srow + i * 32) * 1024 + kn + scol];
            rb[i] = *(const h16x8*)&Wp[(size_t)(n0 + srow + i * 32) * 1024 + kn + scol];
        }

#pragma unroll
        for (int t = 0; t < 2; t++) {
            h16x8 af[4], bf[4];
#pragma unroll
            for (int mi = 0; mi < 4; mi++)
                af[mi] = *(const h16x8*)&Al[wm * 64 + mi * 16 + r][t * 32 + g * 8];
#pragma unroll
            for (int ni = 0; ni < 4; ni++)
                bf[ni] = *(const h16x8*)&Bl[wn * 64 + ni * 16 + r][t * 32 + g * 8];
#pragma unroll
            for (int mi = 0; mi < 4; mi++)
#pragma unroll
                for (int ni = 0; ni < 4; ni++)
                    acc[mi][ni] = MFMA16(af[mi], bf[ni], acc[mi][ni]);
        }
    }

    float bn[4];
#pragma unroll
    for (int ni = 0; ni < 4; ni++) bn[ni] = bias[n0 + wn * 64 + ni * 16 + r];

    if (p == 2) {
        // V: store transposed [bh][hd][s], packed 4 consecutive s per store
        half_t* outp = qkv + (size_t)2 * 4194304;
#pragma unroll
        for (int mi = 0; mi < 4; mi++) {
            int m = m0 + wm * 64 + mi * 16 + g * 4;
            int b = m >> 11, s = m & 2047;
#pragma unroll
            for (int ni = 0; ni < 4; ni++) {
                int n = n0 + wn * 64 + ni * 16 + r;
                int h = n >> 6, hd = n & 63;
                h16x4 pk;
#pragma unroll
                for (int i = 0; i < 4; i++) pk[i] = (half_t)(acc[mi][ni][i] + bn[ni]);
                *(h16x4*)&outp[((size_t)(b * 16 + h) * 64 + hd) * 2048 + s] = pk;
            }
        }
    } else {
        half_t* outp = qkv + (size_t)p * 4194304;
#pragma unroll
        for (int mi = 0; mi < 4; mi++) {
#pragma unroll
            for (int ni = 0; ni < 4; ni++) {
                int n = n0 + wn * 64 + ni * 16 + r;
                int h = n >> 6, hd = n & 63;
#pragma unroll
                for (int i = 0; i < 4; i++) {
                    int m = m0 + wm * 64 + mi * 16 + g * 4 + i;
                    int b = m >> 11, s = m & 2047;
                    float v = acc[mi][ni][i] + bn[ni];
                    outp[(((size_t)(b * 16 + h) * 2048 + s) << 6) + hd] = (half_t)v;
                }
            }
        }
    }
}

// ---------------------------------------------------------------------------
// Kernel 2: flash attention.  grid (S/128=16, B*H=32), block 256 (4 waves).
// Each wave owns 32 q-rows (2 MFMA q-groups) -> K/V LDS fragment reads
// amortized 2x. Swapped QK^T, exp2-domain softmax, XOR-swizzled LDS,
// double-buffered K/V with post-barrier loads, branch-hoisted defer-max.
// ---------------------------------------------------------------------------
__global__ __launch_bounds__(256, 3) void attn_kernel(
    const half_t* __restrict__ Qg,  // [32][2048][64]
    const half_t* __restrict__ Kg,  // [32][2048][64]
    const half_t* __restrict__ Vtg, // [32][64][2048]  (V transposed)
    float* __restrict__ out)        // [B][S][1024]
{
    __shared__ half_t Kl[2][64][64];    // 128B rows, XOR-swizzled 16B slots
    __shared__ half_t Vl[2][64][64];
    __shared__ half_t Pl[4][32][64];

    const int tid = threadIdx.x;
    const int lane = tid & 63, wid = tid >> 6;   // wid 0..3
    const int g = lane >> 4, r = lane & 15;
    const int bh = blockIdx.y;
    const int b = bh >> 4, h = bh & 15;
    const half_t* Qb = Qg + (size_t)bh * 131072;
    const half_t* Kb = Kg + (size_t)bh * 131072;
    const half_t* Vb = Vtg + (size_t)bh * 131072;
    const int q0 = blockIdx.x * 128 + wid * 32;

    // hoisted Q fragments (2 q-groups), pre-scaled by log2(e)
    h16x8 qf[2][2];
#pragma unroll
    for (int qg = 0; qg < 2; qg++)
#pragma unroll
        for (int t = 0; t < 2; t++) {
            qf[qg][t] = *(const h16x8*)&Qb[(size_t)(q0 + qg * 16 + r) * 64 + t * 32 + g * 8];
            qf[qg][t] *= (half_t)1.44269504f;
        }

    f32x4 o[2][4];
#pragma unroll
    for (int qg = 0; qg < 2; qg++)
#pragma unroll
        for (int d = 0; d < 4; d++) o[qg][d] = (f32x4){0.f, 0.f, 0.f, 0.f};
    float m_run[2] = {0.f, 0.f}, l_run[2] = {0.f, 0.f};

    const int srow = tid >> 3;          // 0..31
    const int sslot = tid & 7;          // 16B slot 0..7
    const int sc8 = sslot * 8;

    // prologue: stage tile 0 (swizzled writes), 2 rows each of K and V
#pragma unroll
    for (int half = 0; half < 2; half++) {
        int row = srow + half * 32;
        *(h16x8*)&Kl[0][row][SW(row, sslot)] = *(const h16x8*)&Kb[row * 64 + sc8];
        *(h16x8*)&Vl[0][row][SW(row, sslot)] = *(const h16x8*)&Vb[(size_t)row * 2048 + sc8];
    }

    h16x8 kreg[2], vreg[2];
    int cur = 0;

    auto compute_tile = [&](int cb) {
        // QK^T (swapped): lane holds E[k = kc*16+g*4+i][q = q0+qg*16+r]
        f32x4 e[2][4];
#pragma unroll
        for (int kc = 0; kc < 4; kc++) {
            e[0][kc] = (f32x4){0.f, 0.f, 0.f, 0.f};
            e[1][kc] = (f32x4){0.f, 0.f, 0.f, 0.f};
#pragma unroll
            for (int t = 0; t < 2; t++) {
                h16x8 kf = *(const h16x8*)&Kl[cb][kc * 16 + r][SW(r, t * 4 + g)];
                e[0][kc] = MFMA16(kf, qf[0][t], e[0][kc]);
                e[1][kc] = MFMA16(kf, qf[1][t], e[1][kc]);
            }
        }

#pragma unroll
        for (int qg = 0; qg < 2; qg++) {
            // tile max (feeds only the rare-rescale branch)
            float t0 = fmaxf(fmaxf(e[qg][0][0], e[qg][0][1]), e[qg][0][2]);
            float t1 = fmaxf(fmaxf(e[qg][0][3], e[qg][1][0]), e[qg][1][1]);
            float t2 = fmaxf(fmaxf(e[qg][1][2], e[qg][1][3]), e[qg][2][0]);
            float t3 = fmaxf(fmaxf(e[qg][2][1], e[qg][2][2]), e[qg][2][3]);
            float t4 = fmaxf(fmaxf(e[qg][3][0], e[qg][3][1]), e[qg][3][2]);
            float tm = fmaxf(fmaxf(t0, t1), fmaxf(fmaxf(t2, t3), fmaxf(t4, e[qg][3][3])));
            tm = fmaxf(tm, __shfl_xor(tm, 16));
            tm = fmaxf(tm, __shfl_xor(tm, 32));

            // unconditional exp with the CURRENT m_run
            float ps0 = 0.f, ps1 = 0.f, ps2 = 0.f, ps3 = 0.f;
#pragma unroll
            for (int i = 0; i < 4; i++) { e[qg][0][i] = EXP2(e[qg][0][i] - m_run[qg]); ps0 += e[qg][0][i]; }
#pragma unroll
            for (int i = 0; i < 4; i++) { e[qg][1][i] = EXP2(e[qg][1][i] - m_run[qg]); ps1 += e[qg][1][i]; }
#pragma unroll
            for (int i = 0; i < 4; i++) { e[qg][2][i] = EXP2(e[qg][2][i] - m_run[qg]); ps2 += e[qg][2][i]; }
#pragma unroll
            for (int i = 0; i < 4; i++) { e[qg][3][i] = EXP2(e[qg][3][i] - m_run[qg]); ps3 += e[qg][3][i]; }

            // rare fix-up: a row's max grew by more than 8 (exp2 domain)
            if (!__all(tm <= m_run[qg] + 8.f)) {
                float nm = fmaxf(m_run[qg], tm);
                float sc = EXP2(m_run[qg] - nm);
                m_run[qg] = nm;
                l_run[qg] *= sc;
#pragma unroll
                for (int kc = 0; kc < 4; kc++)
#pragma unroll
                    for (int i = 0; i < 4; i++) e[qg][kc][i] *= sc;
                ps0 *= sc; ps1 *= sc; ps2 *= sc; ps3 *= sc;
#pragma unroll
                for (int i = 0; i < 4; i++) {
                    float sci = __shfl(sc, (lane & 48) | (g * 4 + i));
#pragma unroll
                    for (int d = 0; d < 4; d++) o[qg][d][i] *= sci;
                }
            }

            float ps = (ps0 + ps1) + (ps2 + ps3);
            ps += __shfl_xor(ps, 16);
            ps += __shfl_xor(ps, 32);
            l_run[qg] += ps;

            // P -> per-wave LDS (swizzled b64 writes)
#pragma unroll
            for (int kc = 0; kc < 4; kc++) {
                h16x4 pk;
#pragma unroll
                for (int i = 0; i < 4; i++) pk[i] = (half_t)e[qg][kc][i];
                *(h16x4*)&Pl[wid][qg * 16 + r][SW(r, 2 * kc + (g >> 1)) + (g & 1) * 4] = pk;
            }
        }
        asm volatile("s_waitcnt lgkmcnt(0)" ::: "memory");
        __builtin_amdgcn_sched_barrier(0);

        // PV: O[qg] += P[qg] @ V   (V fragments shared across both q-groups)
#pragma unroll
        for (int ks = 0; ks < 2; ks++) {
            h16x8 pf0 = *(const h16x8*)&Pl[wid][r][SW(r, ks * 4 + g)];
            h16x8 pf1 = *(const h16x8*)&Pl[wid][16 + r][SW(r, ks * 4 + g)];
#pragma unroll
            for (int d = 0; d < 4; d++) {
                h16x8 vf = *(const h16x8*)&Vl[cb][d * 16 + r][SW(r, ks * 4 + g)];
                o[0][d] = MFMA16(pf0, vf, o[0][d]);
                o[1][d] = MFMA16(pf1, vf, o[1][d]);
            }
        }
    };

    for (int kt = 0; kt < 32; ++kt) {
        int ktn = (kt + 1) & 31;   // wraps on last iter (harmless reload)
        __syncthreads();
        // issue next-tile loads AFTER the barrier (no vmcnt drain at s_barrier)
#pragma unroll
        for (int half = 0; half < 2; half++) {
            int row = srow + half * 32;
            kreg[half] = *(const h16x8*)&Kb[ktn * 4096 + row * 64 + sc8];
            vreg[half] = *(const h16x8*)&Vb[(size_t)row * 2048 + ktn * 64 + sc8];
        }
        compute_tile(cur);
#pragma unroll
        for (int half = 0; half < 2; half++) {
            int row = srow + half * 32;
            *(h16x8*)&Kl[cur ^ 1][row][SW(row, sslot)] = kreg[half];
            *(h16x8*)&Vl[cur ^ 1][row][SW(row, sslot)] = vreg[half];
        }
        cur ^= 1;
    }

    // epilogue
#pragma unroll
    for (int qg = 0; qg < 2; qg++)
#pragma unroll
        for (int i = 0; i < 4; i++) {
            float li = __shfl(l_run[qg], (lane & 48) | (g * 4 + i));
            float inv = 1.0f / li;
            int s = q0 + qg * 16 + g * 4 + i;
            float* op = out + (size_t)(b * 2048 + s) * 1024 + h * 64 + r;
#pragma unroll
            for (int d = 0; d < 4; d++) op[d * 16] = o[qg][d][i] * inv;
        }
}

// ---------------------------------------------------------------------------
extern "C" void kernel_launch(void* const* d_in, const int* in_sizes, int n_in,
                              void* d_out, int out_size, void* d_ws, size_t ws_size,
                              hipStream_t stream) {
    const float* x  = (const float*)d_in[0];
    const float* Wq = (const float*)d_in[1];
    const float* bq = (const float*)d_in[2];
    const float* Wk = (const float*)d_in[3];
    const float* bk = (const float*)d_in[4];
    const float* Wv = (const float*)d_in[5];
    const float* bv = (const float*)d_in[6];
    float* out = (float*)d_out;

    half_t* xh  = (half_t*)d_ws;
    half_t* Wt  = (half_t*)((char*)d_ws + (size_t)8 * 1024 * 1024);
    half_t* qkv = (half_t*)((char*)d_ws + (size_t)14 * 1024 * 1024);
    half_t* Qh  = qkv;
    half_t* Kh  = qkv + (size_t)4194304;
    half_t* Vth = qkv + (size_t)8388608;

    cvt_x_kernel<<<2048, 256, 0, stream>>>(x, xh, 524288);
    cvt_w_kernel<<<dim3(32, 32, 3), 256, 0, stream>>>(Wq, Wk, Wv, Wt);
    gemm_qkv_kernel<<<dim3(8, 32, 3), 256, 0, stream>>>(xh, Wt, bq, bk, bv, qkv);
    attn_kernel<<<dim3(16, 32), 256, 0, stream>>>(Qh, Kh, Vth, out);
}